// Round 2
// baseline (257.591 us; speedup 1.0000x reference)
//
#include <hip/hip_runtime.h>
#include <cstddef>

typedef float  f32x4  __attribute__((ext_vector_type(4)));
typedef __bf16 bf16x8 __attribute__((ext_vector_type(8)));
typedef __bf16 bf16x4 __attribute__((ext_vector_type(4)));

#define DEV static __device__ __forceinline__

DEV float sigf(float x){ return 1.f/(1.f+__expf(-x)); }
DEV float tanh_f(float x){
  x = fminf(fmaxf(x, -20.f), 20.f);
  float e = __expf(2.f*x);
  return (e-1.f)/(e+1.f);
}

DEV bf16x8 cvt8(const float4 a, const float4 b){
  bf16x8 r;
  r[0]=(__bf16)a.x; r[1]=(__bf16)a.y; r[2]=(__bf16)a.z; r[3]=(__bf16)a.w;
  r[4]=(__bf16)b.x; r[5]=(__bf16)b.y; r[6]=(__bf16)b.z; r[7]=(__bf16)b.w;
  return r;
}

// ---------------- fragment-layout convert: f32 row-major -> bf16 MFMA tiles ----------
// src: [nTiles][16 rows][512 cols] f32 (rows contiguous). dst tile (gt,sub):
// lane l holds src[gt*16 + (l&15)][sub*32 + (l>>4)*8 .. +8] at dst[(gt*16+sub)*512 + l*8].
__global__ void k_frag(const float* __restrict__ src, __bf16* __restrict__ dst)
{
  const int idx = blockIdx.x*256 + threadIdx.x;
  const int l   = idx & 63;
  const int sub = (idx >> 6) & 15;
  const int gt  = idx >> 10;
  const float* p = src + ((size_t)gt*16 + (l&15))*512 + sub*32 + (l>>4)*8;
  float4 v0 = *(const float4*)p;
  float4 v1 = *(const float4*)(p+4);
  *(bf16x8*)(dst + ((size_t)(gt*16 + sub)*64 + l)*8) = cvt8(v0, v1);
}

// ---------------- ph = h_last @ W_ph^T : (128,256) ----------------
__global__ void k_ph(const float* __restrict__ h0, const float* __restrict__ W_ph,
                     float* __restrict__ ph)
{
  const int b = blockIdx.x, a = threadIdx.x;
  __shared__ float h_s[1024];
  for (int k = a; k < 1024; k += 256) h_s[k] = h0[(size_t)b*1024 + k];
  __syncthreads();
  const float* wr = W_ph + (size_t)a*1024;
  float acc = 0.f;
  for (int k = 0; k < 1024; k += 4){
    float4 w = *(const float4*)(wr + k);
    acc += w.x*h_s[k] + w.y*h_s[k+1] + w.z*h_s[k+2] + w.w*h_s[k+3];
  }
  ph[b*256 + a] = acc;
}

// ---------------- xh[:,0:512]=embed, xh[:,1024:2048]=h0 ----------------
__global__ void k_concat(const float* __restrict__ embed, const float* __restrict__ h0,
                         float* __restrict__ xh)
{
  const int b = blockIdx.x, tid = threadIdx.x;
  *(float2*)(xh + (size_t)b*2048 + tid*2) = *(const float2*)(embed + (size_t)b*512 + tid*2);
  *(float4*)(xh + (size_t)b*2048 + 1024 + tid*4) = *(const float4*)(h0 + (size_t)b*1024 + tid*4);
}

// ---------------- scores: LDS-free, barrier-free MFMA from fragment layout ----------
// block: 128 t-rows x 256 a-cols; 4 waves each own 32 t-rows; K=512 (16 kt).
__global__ __launch_bounds__(256,2) void k_scores(
    const __bf16* __restrict__ encX, const __bf16* __restrict__ wpeX,
    const float* __restrict__ ph, const float* __restrict__ w_fc2,
    float* __restrict__ scores)
{
  const int b  = blockIdx.y;
  const int tc = blockIdx.x;            // t-chunk of 128
  const int tid = threadIdx.x;
  const int w = tid >> 6, l = tid & 63;
  const int la = l & 15, g = l >> 4;

  __shared__ float ph_s[256];
  __shared__ float w2_s[256];
  ph_s[tid] = ph[b*256 + tid];
  w2_s[tid] = w_fc2[tid];
  __syncthreads();

  f32x4 acc[2][16];
  #pragma unroll
  for (int i = 0; i < 2; ++i)
    #pragma unroll
    for (int j = 0; j < 16; ++j) acc[i][j] = (f32x4){0.f,0.f,0.f,0.f};

  const int tt0 = b*32 + tc*8 + w*2;    // first of this wave's two t-tiles
  const __bf16* a0p = encX + (size_t)tt0*16*512 + l*8;
  const __bf16* a1p = a0p + 16*512;
  const __bf16* bp  = wpeX + l*8;

  for (int kt = 0; kt < 16; ++kt){
    bf16x8 af0 = *(const bf16x8*)(a0p + kt*512);
    bf16x8 af1 = *(const bf16x8*)(a1p + kt*512);
    #pragma unroll
    for (int nf = 0; nf < 16; ++nf){
      bf16x8 bf = *(const bf16x8*)(bp + ((size_t)(nf*16 + kt))*512);
      acc[0][nf] = __builtin_amdgcn_mfma_f32_16x16x32_bf16(af0, bf, acc[0][nf], 0,0,0);
      acc[1][nf] = __builtin_amdgcn_mfma_f32_16x16x32_bf16(af1, bf, acc[1][nf], 0,0,0);
    }
  }

  // epilogue: s[t] = sum_a tanh(pe + ph[a]) * w2[a]; D: row=(g*4+r), col=la
  #pragma unroll
  for (int mfi = 0; mfi < 2; ++mfi){
    #pragma unroll
    for (int r = 0; r < 4; ++r){
      float s = 0.f;
      #pragma unroll
      for (int nf = 0; nf < 16; ++nf){
        float v = acc[mfi][nf][r] + ph_s[nf*16 + la];
        s += tanh_f(v) * w2_s[nf*16 + la];
      }
      s += __shfl_xor(s, 1, 16);
      s += __shfl_xor(s, 2, 16);
      s += __shfl_xor(s, 4, 16);
      s += __shfl_xor(s, 8, 16);
      if (la == 0){
        int t = tc*128 + w*32 + mfi*16 + g*4 + r;
        scores[b*512 + t] = s;
      }
    }
  }
}

// ---------------- softmax over T=512 per batch row (in-place ok) ----------------
__global__ void k_softmax(const float* __restrict__ scores, const unsigned char* __restrict__ mask,
                          float* __restrict__ aw)
{
  const int b = blockIdx.x, tid = threadIdx.x;
  float s0 = scores[b*512 + tid];
  float s1 = scores[b*512 + 256 + tid];
  if (mask[b*512 + tid])       s0 = -1e30f;
  if (mask[b*512 + 256 + tid]) s1 = -1e30f;
  float m = fmaxf(s0, s1);
  #pragma unroll
  for (int o = 32; o; o >>= 1) m = fmaxf(m, __shfl_xor(m, o, 64));
  __shared__ float redm[4], reds[4];
  const int wv = tid >> 6, lx = tid & 63;
  if (lx == 0) redm[wv] = m;
  __syncthreads();
  m = fmaxf(fmaxf(redm[0], redm[1]), fmaxf(redm[2], redm[3]));
  float e0 = __expf(s0 - m), e1 = __expf(s1 - m);
  float ss = e0 + e1;
  #pragma unroll
  for (int o = 32; o; o >>= 1) ss += __shfl_xor(ss, o, 64);
  if (lx == 0) reds[wv] = ss;
  __syncthreads();
  ss = reds[0] + reds[1] + reds[2] + reds[3];
  float inv = 1.f / ss;
  aw[b*512 + tid]       = e0 * inv;
  aw[b*512 + 256 + tid] = e1 * inv;
}

// ---------------- ctxt from fragment layout: grid (128 b, 16 kt) ----------------
// ctxt[b, kt*32 + g*8 + j] = sum_t aw[b,t] * enc[b,t,e]
__global__ void k_ctxt(const __bf16* __restrict__ encX, const float* __restrict__ aw,
                       float* __restrict__ xh, float* __restrict__ hc)
{
  const int b = blockIdx.x, kt = blockIdx.y;
  const int tid = threadIdx.x, w = tid >> 6, l = tid & 63;
  const int la = l & 15, g = l >> 4;
  __shared__ float aw_s[512];
  aw_s[tid]       = aw[b*512 + tid];
  aw_s[256 + tid] = aw[b*512 + 256 + tid];
  __syncthreads();

  float s[8] = {0.f,0.f,0.f,0.f,0.f,0.f,0.f,0.f};
  const __bf16* p = encX + ((size_t)(b*32)*16 + kt)*512 + l*8;
  for (int tt = w; tt < 32; tt += 4){
    bf16x8 v = *(const bf16x8*)(p + (size_t)tt*16*512);
    float wgt = aw_s[tt*16 + la];
    #pragma unroll
    for (int j = 0; j < 8; ++j) s[j] += wgt * (float)v[j];
  }
  #pragma unroll
  for (int j = 0; j < 8; ++j){
    s[j] += __shfl_xor(s[j], 1, 16);
    s[j] += __shfl_xor(s[j], 2, 16);
    s[j] += __shfl_xor(s[j], 4, 16);
    s[j] += __shfl_xor(s[j], 8, 16);
  }
  __shared__ float red[4][4][8];
  if (la == 0){
    #pragma unroll
    for (int j = 0; j < 8; ++j) red[w][g][j] = s[j];
  }
  __syncthreads();
  if (tid < 32){
    const int g2 = tid >> 3, j = tid & 7;
    float v = red[0][g2][j] + red[1][g2][j] + red[2][g2][j] + red[3][g2][j];
    const int e = kt*32 + g2*8 + j;
    xh[(size_t)b*2048 + 512 + e] = v;
    hc[(size_t)b*1536 + 1024 + e] = v;
  }
}

// ---------------- generic C[128,N] = act(A[128,K] @ [W1|W2]^T + b1 + b2) ----------------
__global__ __launch_bounds__(256,2) void k_gemm(
    const float* __restrict__ A, int lda,
    const float* __restrict__ W1, int ldw1,
    const float* __restrict__ W2, int ldw2, int ksplit,
    const float* __restrict__ bias1, const float* __restrict__ bias2,
    float* __restrict__ C, int ldc, int K, int act)
{
  const int jt = blockIdx.x * 32;
  const int tid = threadIdx.x;
  const int w = tid >> 6, lane = tid & 63;
  const int la = lane & 15, g = lane >> 4;

  __shared__ __align__(16) __bf16 A_s[128][40];
  __shared__ __align__(16) __bf16 B_s[32][40];

  f32x4 acc[2][2];
  #pragma unroll
  for (int i = 0; i < 2; ++i)
    #pragma unroll
    for (int j = 0; j < 2; ++j) acc[i][j] = (f32x4){0.f,0.f,0.f,0.f};

  const int ar = tid >> 1, ac = (tid & 1) * 16;
  const int br = tid >> 3, bc = (tid & 7) * 4;

  for (int kk = 0; kk < K; kk += 32){
    {
      const float* p = A + (size_t)ar*lda + kk + ac;
      float4 v0 = *(const float4*)(p);
      float4 v1 = *(const float4*)(p+4);
      float4 v2 = *(const float4*)(p+8);
      float4 v3 = *(const float4*)(p+12);
      *(bf16x8*)&A_s[ar][ac]   = cvt8(v0,v1);
      *(bf16x8*)&A_s[ar][ac+8] = cvt8(v2,v3);
    }
    {
      const float* wp = (kk < ksplit)
          ? (W1 + (size_t)(jt+br)*ldw1 + kk + bc)
          : (W2 + (size_t)(jt+br)*ldw2 + (kk - ksplit) + bc);
      float4 v = *(const float4*)wp;
      bf16x4 bv;
      bv[0]=(__bf16)v.x; bv[1]=(__bf16)v.y; bv[2]=(__bf16)v.z; bv[3]=(__bf16)v.w;
      *(bf16x4*)&B_s[br][bc] = bv;
    }
    __syncthreads();
    bf16x8 a0 = *(const bf16x8*)&A_s[w*32 + la][g*8];
    bf16x8 a1 = *(const bf16x8*)&A_s[w*32 + 16 + la][g*8];
    bf16x8 b0 = *(const bf16x8*)&B_s[la][g*8];
    bf16x8 b1 = *(const bf16x8*)&B_s[16 + la][g*8];
    acc[0][0] = __builtin_amdgcn_mfma_f32_16x16x32_bf16(a0, b0, acc[0][0], 0,0,0);
    acc[0][1] = __builtin_amdgcn_mfma_f32_16x16x32_bf16(a0, b1, acc[0][1], 0,0,0);
    acc[1][0] = __builtin_amdgcn_mfma_f32_16x16x32_bf16(a1, b0, acc[1][0], 0,0,0);
    acc[1][1] = __builtin_amdgcn_mfma_f32_16x16x32_bf16(a1, b1, acc[1][1], 0,0,0);
    __syncthreads();
  }

  #pragma unroll
  for (int mfi = 0; mfi < 2; ++mfi)
    #pragma unroll
    for (int nf = 0; nf < 2; ++nf)
      #pragma unroll
      for (int r = 0; r < 4; ++r){
        int m = w*32 + mfi*16 + g*4 + r;
        int j = jt + nf*16 + la;
        float v = acc[mfi][nf][r];
        if (bias1) v += bias1[j];
        if (bias2) v += bias2[j];
        if (act == 1) v = tanh_f(v);
        C[(size_t)m*ldc + j] = v;
      }
}

// ---------------- LSTM pointwise: h1, c1 ----------------
__global__ void k_lstm(const float* __restrict__ gates, const float* __restrict__ c0,
                       float* __restrict__ out, float* __restrict__ hc)
{
  const int idx = blockIdx.x*256 + threadIdx.x;   // 0..131071
  const int b = idx >> 10, h = idx & 1023;
  const float* gp = gates + (size_t)b*4096;
  float gi = gp[h], gf = gp[1024 + h], gg = gp[2048 + h], go = gp[3072 + h];
  float c1 = sigf(gf)*c0[idx] + sigf(gi)*tanh_f(gg);
  float h1 = sigf(go)*tanh_f(c1);
  out[131072 + idx] = h1;
  out[262144 + idx] = c1;
  hc[(size_t)b*1536 + h] = h1;
}

extern "C" void kernel_launch(void* const* d_in, const int* in_sizes, int n_in,
                              void* d_out, int out_size, void* d_ws, size_t ws_size,
                              hipStream_t stream)
{
  const float* embed  = (const float*)d_in[0];
  const float* h0     = (const float*)d_in[1];
  const float* c0     = (const float*)d_in[2];
  const float* enc    = (const float*)d_in[3];
  const float* W_ph   = (const float*)d_in[4];
  const float* W_pe   = (const float*)d_in[5];
  const float* w_fc2  = (const float*)d_in[6];
  const float* W_ih   = (const float*)d_in[7];
  const float* W_hh   = (const float*)d_in[8];
  const float* b_ih   = (const float*)d_in[9];
  const float* b_hh   = (const float*)d_in[10];
  const float* W_proj = (const float*)d_in[11];
  const float* b_proj = (const float*)d_in[12];
  const unsigned char* mask = (const unsigned char*)d_in[13];

  float* ws     = (float*)d_ws;
  float* ph     = ws;                  //  32768
  float* scores = ws + 32768;          //  65536 (aw in place)
  float* xh     = ws + 98304;          // 262144 (128x2048: [embed|ctxt|h])
  float* gates  = ws + 360448;         // 524288 (128x4096)
  float* hc     = ws + 884736;         // 196608 (128x1536: [h1|ctxt])
  __bf16* encX  = (__bf16*)(ws + 1081344);            // 33,554,432 bf16
  __bf16* wpeX  = encX + (size_t)33554432;            //    131,072 bf16
  float* out    = (float*)d_out;

  k_frag  <<<16384, 256, 0, stream>>>(enc, encX);     // 128*32 tiles
  k_frag  <<<64,    256, 0, stream>>>(W_pe, wpeX);    // 16 tiles
  k_ph    <<<128, 256, 0, stream>>>(h0, W_ph, ph);
  k_concat<<<128, 256, 0, stream>>>(embed, h0, xh);
  k_scores<<<dim3(4,128), 256, 0, stream>>>(encX, wpeX, ph, w_fc2, scores);
  k_softmax<<<128, 256, 0, stream>>>(scores, mask, scores);
  k_ctxt  <<<dim3(128,16), 256, 0, stream>>>(encX, scores, xh, hc);
  k_gemm  <<<128, 256, 0, stream>>>(xh, 2048, W_ih, 1024, W_hh, 1024, 1024,
                                    b_ih, b_hh, gates, 4096, 2048, 0);
  k_lstm  <<<512, 256, 0, stream>>>(gates, c0, out, hc);
  k_gemm  <<<32, 256, 0, stream>>>(hc, 1536, W_proj, 1536, nullptr, 0, 1536,
                                   b_proj, nullptr, out, 1024, 1536, 1);
}

// Round 3
// 195.366 us; speedup vs baseline: 1.3185x; 1.3185x over previous
//
#include <hip/hip_runtime.h>
#include <cstddef>

typedef float  f32x4  __attribute__((ext_vector_type(4)));
typedef __bf16 bf16x8 __attribute__((ext_vector_type(8)));
typedef __bf16 bf16x4 __attribute__((ext_vector_type(4)));

#define DEV static __device__ __forceinline__

DEV float sigf(float x){ return 1.f/(1.f+__expf(-x)); }
DEV float tanh_f(float x){
  x = fminf(fmaxf(x, -20.f), 20.f);
  float e = __expf(2.f*x);
  return (e-1.f)/(e+1.f);
}

DEV bf16x8 cvt8(const float4 a, const float4 b){
  bf16x8 r;
  r[0]=(__bf16)a.x; r[1]=(__bf16)a.y; r[2]=(__bf16)a.z; r[3]=(__bf16)a.w;
  r[4]=(__bf16)b.x; r[5]=(__bf16)b.y; r[6]=(__bf16)b.z; r[7]=(__bf16)b.w;
  return r;
}

// ---------------- fragment-layout convert (W_pe only): f32 -> bf16 MFMA tiles ----
// lane l of tile (gt,sub) holds src[gt*16 + (l&15)][sub*32 + (l>>4)*8 .. +8]
__global__ void k_frag(const float* __restrict__ src, __bf16* __restrict__ dst)
{
  const int idx = blockIdx.x*256 + threadIdx.x;
  const int l   = idx & 63;
  const int sub = (idx >> 6) & 15;
  const int gt  = idx >> 10;
  const float* p = src + ((size_t)gt*16 + (l&15))*512 + sub*32 + (l>>4)*8;
  float4 v0 = *(const float4*)p;
  float4 v1 = *(const float4*)(p+4);
  *(bf16x8*)(dst + ((size_t)(gt*16 + sub)*64 + l)*8) = cvt8(v0, v1);
}

// ---------------- ph = h_last @ W_ph^T : (128,256) ----------------
__global__ void k_ph(const float* __restrict__ h0, const float* __restrict__ W_ph,
                     float* __restrict__ ph)
{
  const int b = blockIdx.x, a = threadIdx.x;
  __shared__ float h_s[1024];
  for (int k = a; k < 1024; k += 256) h_s[k] = h0[(size_t)b*1024 + k];
  __syncthreads();
  const float* wr = W_ph + (size_t)a*1024;
  float acc = 0.f;
  for (int k = 0; k < 1024; k += 4){
    float4 w = *(const float4*)(wr + k);
    acc += w.x*h_s[k] + w.y*h_s[k+1] + w.z*h_s[k+2] + w.w*h_s[k+3];
  }
  ph[b*256 + a] = acc;
}

// ---------------- xh[:,0:512]=embed, xh[:,1024:2048]=h0 ----------------
__global__ void k_concat(const float* __restrict__ embed, const float* __restrict__ h0,
                         float* __restrict__ xh)
{
  const int b = blockIdx.x, tid = threadIdx.x;
  *(float2*)(xh + (size_t)b*2048 + tid*2) = *(const float2*)(embed + (size_t)b*512 + tid*2);
  *(float4*)(xh + (size_t)b*2048 + 1024 + tid*4) = *(const float4*)(h0 + (size_t)b*1024 + tid*4);
}

// ---------------- scores: double-buffered LDS pipeline, f32 enc input ----------
// block: 128 t-rows x 256 a-cols, 4 waves (2 t-tiles each), K=512 in 16 steps.
__global__ __launch_bounds__(256,2) void k_scores(
    const float* __restrict__ enc, const __bf16* __restrict__ wpeX,
    const float* __restrict__ ph, const float* __restrict__ w_fc2,
    float* __restrict__ scores)
{
  const int b  = blockIdx.y;
  const int tc = blockIdx.x;            // t-chunk of 128
  const int tid = threadIdx.x;
  const int w = tid >> 6, l = tid & 63;
  const int la = l & 15, g = l >> 4;

  // fragment-ordered LDS: slot s = tile*64 + lane, 16B per slot
  __shared__ __align__(16) __bf16 A_s[2][8*64*8];    //  8 t-tiles, 8KB per buf
  __shared__ __align__(16) __bf16 B_s[2][16*64*8];   // 16 a-tiles, 16KB per buf
  __shared__ float ph_s[256], w2_s[256];

  ph_s[tid] = ph[b*256 + tid];
  w2_s[tid] = w_fc2[tid];

  // A staging: 2 slots/thread (s0=tid -> tiles 0-3, s1=tid+256 -> tiles 4-7)
  const int s0 = tid, s1 = tid + 256;
  const float* ag0 = enc + ((size_t)b*512 + tc*128 + (s0>>6)*16 + (s0&15))*512 + ((s0>>4)&3)*8;
  const float* ag1 = enc + ((size_t)b*512 + tc*128 + (s1>>6)*16 + (s1&15))*512 + ((s1>>4)&3)*8;
  // B staging: 4 slots/thread, slot s=tid+j*256: nf = s>>6, lane = s&63
  const __bf16* bg0 = wpeX + ((size_t)((tid>>6)     ))*8192 + (tid&63)*8;
  const __bf16* bg1 = bg0 + (size_t)4*8192;
  const __bf16* bg2 = bg0 + (size_t)8*8192;
  const __bf16* bg3 = bg0 + (size_t)12*8192;

  f32x4 acc[2][16];
  #pragma unroll
  for (int i = 0; i < 2; ++i)
    #pragma unroll
    for (int j = 0; j < 16; ++j) acc[i][j] = (f32x4){0.f,0.f,0.f,0.f};

  float4 ar00, ar01, ar10, ar11;
  bf16x8 br0, br1, br2, br3;

  // prologue: stage kt=0 into buf 0
  ar00 = *(const float4*)(ag0);  ar01 = *(const float4*)(ag0 + 4);
  ar10 = *(const float4*)(ag1);  ar11 = *(const float4*)(ag1 + 4);
  br0 = *(const bf16x8*)(bg0);   br1 = *(const bf16x8*)(bg1);
  br2 = *(const bf16x8*)(bg2);   br3 = *(const bf16x8*)(bg3);
  *(bf16x8*)&A_s[0][s0*8] = cvt8(ar00, ar01);
  *(bf16x8*)&A_s[0][s1*8] = cvt8(ar10, ar11);
  *(bf16x8*)&B_s[0][(size_t)(tid        )*8] = br0;
  *(bf16x8*)&B_s[0][(size_t)(tid +  256 )*8] = br1;
  *(bf16x8*)&B_s[0][(size_t)(tid +  512 )*8] = br2;
  *(bf16x8*)&B_s[0][(size_t)(tid +  768 )*8] = br3;

  for (int kt = 0; kt < 16; ++kt){
    const int cur = kt & 1;
    __syncthreads();                       // buf[cur] writes (and ph_s/w2_s) visible
    if (kt < 15){                          // issue next-tile loads early (hide under MFMA)
      const int ko = (kt+1)*32;
      ar00 = *(const float4*)(ag0 + ko);  ar01 = *(const float4*)(ag0 + ko + 4);
      ar10 = *(const float4*)(ag1 + ko);  ar11 = *(const float4*)(ag1 + ko + 4);
      const int kb = (kt+1)*512;
      br0 = *(const bf16x8*)(bg0 + kb);   br1 = *(const bf16x8*)(bg1 + kb);
      br2 = *(const bf16x8*)(bg2 + kb);   br3 = *(const bf16x8*)(bg3 + kb);
    }
    // compute phase: conflict-free contiguous ds_read_b128
    bf16x8 af0 = *(const bf16x8*)&A_s[cur][(size_t)(w*2+0)*512 + l*8];
    bf16x8 af1 = *(const bf16x8*)&A_s[cur][(size_t)(w*2+1)*512 + l*8];
    #pragma unroll
    for (int nf = 0; nf < 16; ++nf){
      bf16x8 bf = *(const bf16x8*)&B_s[cur][(size_t)nf*512 + l*8];
      acc[0][nf] = __builtin_amdgcn_mfma_f32_16x16x32_bf16(af0, bf, acc[0][nf], 0,0,0);
      acc[1][nf] = __builtin_amdgcn_mfma_f32_16x16x32_bf16(af1, bf, acc[1][nf], 0,0,0);
    }
    __syncthreads();                       // reads of buf[cur^1] finished last iter; writes safe
    if (kt < 15){
      const int nxt = cur ^ 1;
      *(bf16x8*)&A_s[nxt][s0*8] = cvt8(ar00, ar01);
      *(bf16x8*)&A_s[nxt][s1*8] = cvt8(ar10, ar11);
      *(bf16x8*)&B_s[nxt][(size_t)(tid       )*8] = br0;
      *(bf16x8*)&B_s[nxt][(size_t)(tid +  256)*8] = br1;
      *(bf16x8*)&B_s[nxt][(size_t)(tid +  512)*8] = br2;
      *(bf16x8*)&B_s[nxt][(size_t)(tid +  768)*8] = br3;
    }
  }

  // epilogue: s[t] = sum_a tanh(pe + ph[a]) * w2[a]; D: row=(g*4+r), col=la
  #pragma unroll
  for (int mfi = 0; mfi < 2; ++mfi){
    #pragma unroll
    for (int r = 0; r < 4; ++r){
      float s = 0.f;
      #pragma unroll
      for (int nf = 0; nf < 16; ++nf){
        float v = acc[mfi][nf][r] + ph_s[nf*16 + la];
        s += tanh_f(v) * w2_s[nf*16 + la];
      }
      s += __shfl_xor(s, 1, 16);
      s += __shfl_xor(s, 2, 16);
      s += __shfl_xor(s, 4, 16);
      s += __shfl_xor(s, 8, 16);
      if (la == 0){
        int t = tc*128 + w*32 + mfi*16 + g*4 + r;
        scores[b*512 + t] = s;
      }
    }
  }
}

// ---------------- softmax over T=512 per batch row (in-place ok) ----------------
__global__ void k_softmax(const float* __restrict__ scores, const unsigned char* __restrict__ mask,
                          float* __restrict__ aw)
{
  const int b = blockIdx.x, tid = threadIdx.x;
  float s0 = scores[b*512 + tid];
  float s1 = scores[b*512 + 256 + tid];
  if (mask[b*512 + tid])       s0 = -1e30f;
  if (mask[b*512 + 256 + tid]) s1 = -1e30f;
  float m = fmaxf(s0, s1);
  #pragma unroll
  for (int o = 32; o; o >>= 1) m = fmaxf(m, __shfl_xor(m, o, 64));
  __shared__ float redm[4], reds[4];
  const int wv = tid >> 6, lx = tid & 63;
  if (lx == 0) redm[wv] = m;
  __syncthreads();
  m = fmaxf(fmaxf(redm[0], redm[1]), fmaxf(redm[2], redm[3]));
  float e0 = __expf(s0 - m), e1 = __expf(s1 - m);
  float ss = e0 + e1;
  #pragma unroll
  for (int o = 32; o; o >>= 1) ss += __shfl_xor(ss, o, 64);
  if (lx == 0) reds[wv] = ss;
  __syncthreads();
  ss = reds[0] + reds[1] + reds[2] + reds[3];
  float inv = 1.f / ss;
  aw[b*512 + tid]       = e0 * inv;
  aw[b*512 + 256 + tid] = e1 * inv;
}

// ---------------- ctxt partials (f32 enc, float4/lane, 2-way t-split) ----------
__global__ void k_ctxt(const float* __restrict__ enc, const float* __restrict__ aw,
                       float* __restrict__ part)
{
  const int b = blockIdx.x, q = blockIdx.y, tid = threadIdx.x;
  const int tr = tid >> 7, ec = tid & 127;
  __shared__ float aw_s[128];
  if (tid < 128) aw_s[tid] = aw[b*512 + q*128 + tid];
  __syncthreads();
  const float* ep = enc + ((size_t)b*512 + q*128 + tr*64)*512 + ec*4;
  f32x4 s = {0.f,0.f,0.f,0.f};
  for (int t = 0; t < 64; ++t){
    float wgt = aw_s[tr*64 + t];
    f32x4 e = *(const f32x4*)(ep + (size_t)t*512);
    s += e * wgt;
  }
  __shared__ f32x4 red[128];
  if (tr == 1) red[ec] = s;
  __syncthreads();
  if (tr == 0){
    s += red[ec];
    *(f32x4*)(part + ((size_t)q*128 + b)*512 + ec*4) = s;
  }
}

// ---------------- finalize ctxt -> xh[:,512:1024], hc[:,1024:1536] ----------------
__global__ void k_ctxt_fin(const float* __restrict__ part, float* __restrict__ xh,
                           float* __restrict__ hc)
{
  const int b = blockIdx.x, tid = threadIdx.x;
  const int e = tid*2;
  float sx = 0.f, sy = 0.f;
  #pragma unroll
  for (int q = 0; q < 4; ++q){
    float2 p = *(const float2*)(part + ((size_t)q*128 + b)*512 + e);
    sx += p.x; sy += p.y;
  }
  float2 r; r.x = sx; r.y = sy;
  *(float2*)(xh + (size_t)b*2048 + 512 + e) = r;
  *(float2*)(hc + (size_t)b*1536 + 1024 + e) = r;
}

// ---------------- generic C[128,N] = act(A[128,K] @ [W1|W2]^T + b1 + b2) ----------------
__global__ __launch_bounds__(256,2) void k_gemm(
    const float* __restrict__ A, int lda,
    const float* __restrict__ W1, int ldw1,
    const float* __restrict__ W2, int ldw2, int ksplit,
    const float* __restrict__ bias1, const float* __restrict__ bias2,
    float* __restrict__ C, int ldc, int K, int act)
{
  const int jt = blockIdx.x * 32;
  const int tid = threadIdx.x;
  const int w = tid >> 6, lane = tid & 63;
  const int la = lane & 15, g = lane >> 4;

  __shared__ __align__(16) __bf16 A_s[128][40];
  __shared__ __align__(16) __bf16 B_s[32][40];

  f32x4 acc[2][2];
  #pragma unroll
  for (int i = 0; i < 2; ++i)
    #pragma unroll
    for (int j = 0; j < 2; ++j) acc[i][j] = (f32x4){0.f,0.f,0.f,0.f};

  const int ar = tid >> 1, ac = (tid & 1) * 16;
  const int br = tid >> 3, bc = (tid & 7) * 4;

  for (int kk = 0; kk < K; kk += 32){
    {
      const float* p = A + (size_t)ar*lda + kk + ac;
      float4 v0 = *(const float4*)(p);
      float4 v1 = *(const float4*)(p+4);
      float4 v2 = *(const float4*)(p+8);
      float4 v3 = *(const float4*)(p+12);
      *(bf16x8*)&A_s[ar][ac]   = cvt8(v0,v1);
      *(bf16x8*)&A_s[ar][ac+8] = cvt8(v2,v3);
    }
    {
      const float* wp = (kk < ksplit)
          ? (W1 + (size_t)(jt+br)*ldw1 + kk + bc)
          : (W2 + (size_t)(jt+br)*ldw2 + (kk - ksplit) + bc);
      float4 v = *(const float4*)wp;
      bf16x4 bv;
      bv[0]=(__bf16)v.x; bv[1]=(__bf16)v.y; bv[2]=(__bf16)v.z; bv[3]=(__bf16)v.w;
      *(bf16x4*)&B_s[br][bc] = bv;
    }
    __syncthreads();
    bf16x8 a0 = *(const bf16x8*)&A_s[w*32 + la][g*8];
    bf16x8 a1 = *(const bf16x8*)&A_s[w*32 + 16 + la][g*8];
    bf16x8 b0 = *(const bf16x8*)&B_s[la][g*8];
    bf16x8 b1 = *(const bf16x8*)&B_s[16 + la][g*8];
    acc[0][0] = __builtin_amdgcn_mfma_f32_16x16x32_bf16(a0, b0, acc[0][0], 0,0,0);
    acc[0][1] = __builtin_amdgcn_mfma_f32_16x16x32_bf16(a0, b1, acc[0][1], 0,0,0);
    acc[1][0] = __builtin_amdgcn_mfma_f32_16x16x32_bf16(a1, b0, acc[1][0], 0,0,0);
    acc[1][1] = __builtin_amdgcn_mfma_f32_16x16x32_bf16(a1, b1, acc[1][1], 0,0,0);
    __syncthreads();
  }

  #pragma unroll
  for (int mfi = 0; mfi < 2; ++mfi)
    #pragma unroll
    for (int nf = 0; nf < 2; ++nf)
      #pragma unroll
      for (int r = 0; r < 4; ++r){
        int m = w*32 + mfi*16 + g*4 + r;
        int j = jt + nf*16 + la;
        float v = acc[mfi][nf][r];
        if (bias1) v += bias1[j];
        if (bias2) v += bias2[j];
        if (act == 1) v = tanh_f(v);
        C[(size_t)m*ldc + j] = v;
      }
}

// ---------------- LSTM pointwise: h1, c1 ----------------
__global__ void k_lstm(const float* __restrict__ gates, const float* __restrict__ c0,
                       float* __restrict__ out, float* __restrict__ hc)
{
  const int idx = blockIdx.x*256 + threadIdx.x;   // 0..131071
  const int b = idx >> 10, h = idx & 1023;
  const float* gp = gates + (size_t)b*4096;
  float gi = gp[h], gf = gp[1024 + h], gg = gp[2048 + h], go = gp[3072 + h];
  float c1 = sigf(gf)*c0[idx] + sigf(gi)*tanh_f(gg);
  float h1 = sigf(go)*tanh_f(c1);
  out[131072 + idx] = h1;
  out[262144 + idx] = c1;
  hc[(size_t)b*1536 + h] = h1;
}

extern "C" void kernel_launch(void* const* d_in, const int* in_sizes, int n_in,
                              void* d_out, int out_size, void* d_ws, size_t ws_size,
                              hipStream_t stream)
{
  const float* embed  = (const float*)d_in[0];
  const float* h0     = (const float*)d_in[1];
  const float* c0     = (const float*)d_in[2];
  const float* enc    = (const float*)d_in[3];
  const float* W_ph   = (const float*)d_in[4];
  const float* W_pe   = (const float*)d_in[5];
  const float* w_fc2  = (const float*)d_in[6];
  const float* W_ih   = (const float*)d_in[7];
  const float* W_hh   = (const float*)d_in[8];
  const float* b_ih   = (const float*)d_in[9];
  const float* b_hh   = (const float*)d_in[10];
  const float* W_proj = (const float*)d_in[11];
  const float* b_proj = (const float*)d_in[12];
  const unsigned char* mask = (const unsigned char*)d_in[13];

  float* ws     = (float*)d_ws;
  float* ph     = ws;                  //  32768
  float* scores = ws + 32768;          //  65536 (aw in place)
  float* part   = ws + 98304;          // 262144 (4 x 128 x 512)
  float* xh     = ws + 360448;         // 262144 (128x2048: [embed|ctxt|h])
  float* gates  = ws + 622592;         // 524288 (128x4096)
  float* hc     = ws + 1146880;        // 196608 (128x1536: [h1|ctxt])
  __bf16* wpeX  = (__bf16*)(ws + 1343488);   // 131072 bf16
  float* out    = (float*)d_out;

  k_frag  <<<64, 256, 0, stream>>>(W_pe, wpeX);      // 16 tiles
  k_ph    <<<128, 256, 0, stream>>>(h0, W_ph, ph);
  k_concat<<<128, 256, 0, stream>>>(embed, h0, xh);
  k_scores<<<dim3(4,128), 256, 0, stream>>>(enc, wpeX, ph, w_fc2, scores);
  k_softmax<<<128, 256, 0, stream>>>(scores, mask, scores);
  k_ctxt  <<<dim3(128,4), 256, 0, stream>>>(enc, scores, part);
  k_ctxt_fin<<<128, 256, 0, stream>>>(part, xh, hc);
  k_gemm  <<<128, 256, 0, stream>>>(xh, 2048, W_ih, 1024, W_hh, 1024, 1024,
                                    b_ih, b_hh, gates, 4096, 2048, 0);
  k_lstm  <<<512, 256, 0, stream>>>(gates, c0, out, hc);
  k_gemm  <<<32, 256, 0, stream>>>(hc, 1536, W_proj, 1536, nullptr, 0, 1536,
                                   b_proj, nullptr, out, 1024, 1536, 1);
}

// Round 4
// 157.428 us; speedup vs baseline: 1.6362x; 1.2410x over previous
//
#include <hip/hip_runtime.h>
#include <cstddef>

typedef float  f32x4  __attribute__((ext_vector_type(4)));
typedef __bf16 bf16x8 __attribute__((ext_vector_type(8)));
typedef __bf16 bf16x4 __attribute__((ext_vector_type(4)));

#define DEV static __device__ __forceinline__

DEV float sigf(float x){ return 1.f/(1.f+__expf(-x)); }
DEV float tanh_f(float x){
  x = fminf(fmaxf(x, -20.f), 20.f);
  float e = __expf(2.f*x);
  return (e-1.f)/(e+1.f);
}

DEV bf16x8 cvt8(const float4 a, const float4 b){
  bf16x8 r;
  r[0]=(__bf16)a.x; r[1]=(__bf16)a.y; r[2]=(__bf16)a.z; r[3]=(__bf16)a.w;
  r[4]=(__bf16)b.x; r[5]=(__bf16)b.y; r[6]=(__bf16)b.z; r[7]=(__bf16)b.w;
  return r;
}

// ---------------- fragment-layout convert (W_pe only): f32 -> bf16 MFMA tiles ----
// lane l of tile (gt,sub) holds src[gt*16 + (l&15)][sub*32 + (l>>4)*8 .. +8]
__global__ void k_frag(const float* __restrict__ src, __bf16* __restrict__ dst)
{
  const int idx = blockIdx.x*256 + threadIdx.x;
  const int l   = idx & 63;
  const int sub = (idx >> 6) & 15;
  const int gt  = idx >> 10;
  const float* p = src + ((size_t)gt*16 + (l&15))*512 + sub*32 + (l>>4)*8;
  float4 v0 = *(const float4*)p;
  float4 v1 = *(const float4*)(p+4);
  *(bf16x8*)(dst + ((size_t)(gt*16 + sub)*64 + l)*8) = cvt8(v0, v1);
}

// ---------------- ph = h_last @ W_ph^T : (128,256) ----------------
__global__ void k_ph(const float* __restrict__ h0, const float* __restrict__ W_ph,
                     float* __restrict__ ph)
{
  const int b = blockIdx.x, a = threadIdx.x;
  __shared__ float h_s[1024];
  for (int k = a; k < 1024; k += 256) h_s[k] = h0[(size_t)b*1024 + k];
  __syncthreads();
  const float* wr = W_ph + (size_t)a*1024;
  float acc = 0.f;
  for (int k = 0; k < 1024; k += 4){
    float4 w = *(const float4*)(wr + k);
    acc += w.x*h_s[k] + w.y*h_s[k+1] + w.z*h_s[k+2] + w.w*h_s[k+3];
  }
  ph[b*256 + a] = acc;
}

// ---------------- xh[:,0:512]=embed, xh[:,1024:2048]=h0 ----------------
__global__ void k_concat(const float* __restrict__ embed, const float* __restrict__ h0,
                         float* __restrict__ xh)
{
  const int b = blockIdx.x, tid = threadIdx.x;
  *(float2*)(xh + (size_t)b*2048 + tid*2) = *(const float2*)(embed + (size_t)b*512 + tid*2);
  *(float4*)(xh + (size_t)b*2048 + 1024 + tid*4) = *(const float4*)(h0 + (size_t)b*1024 + tid*4);
}

// ---------------- scores: A via dbuf LDS, B direct L2->reg one-kt-ahead ----------
// block: 64 t-rows x 256 a-cols, 4 waves (1 t-tile each), K=512 in 16 steps.
__global__ __launch_bounds__(256,2) void k_scores(
    const float* __restrict__ enc, const __bf16* __restrict__ wpeX,
    const float* __restrict__ ph, const float* __restrict__ w_fc2,
    float* __restrict__ scores)
{
  const int b  = blockIdx.y;
  const int tc = blockIdx.x;            // t-chunk of 64
  const int tid = threadIdx.x;
  const int w = tid >> 6, l = tid & 63;
  const int la = l & 15, g = l >> 4;

  __shared__ __align__(16) __bf16 A_s[2][256*8];   // 4 t-tiles x 64 lanes x 8, 4KB/buf
  __shared__ float ph_s[256], w2_s[256];
  ph_s[tid] = ph[b*256 + tid];
  w2_s[tid] = w_fc2[tid];

  const float* ag = enc + ((size_t)b*512 + tc*64 + ((tid>>6)*16 + (tid&15)))*512
                        + ((tid>>4)&3)*8;
  const __bf16* bg = wpeX + (size_t)l*8;

  f32x4 acc[16];
  #pragma unroll
  for (int j = 0; j < 16; ++j) acc[j] = (f32x4){0.f,0.f,0.f,0.f};

  bf16x8 b0[16], b1[16];
  float4 a0r, a1r;

  // prologue: kt=0
  a0r = *(const float4*)ag;  a1r = *(const float4*)(ag + 4);
  #pragma unroll
  for (int nf = 0; nf < 16; ++nf)
    b0[nf] = *(const bf16x8*)(bg + (size_t)(nf*16)*512);
  *(bf16x8*)&A_s[0][tid*8] = cvt8(a0r, a1r);

#define SCORE_STEP(CUR, BCUR, BNXT, KT)                                       \
  {                                                                           \
    __syncthreads();                                                          \
    if ((KT) < 15){                                                           \
      const int ko = ((KT)+1)*32;                                             \
      a0r = *(const float4*)(ag + ko);  a1r = *(const float4*)(ag + ko + 4);  \
      _Pragma("unroll")                                                       \
      for (int nf = 0; nf < 16; ++nf)                                         \
        BNXT[nf] = *(const bf16x8*)(bg + (size_t)(nf*16 + (KT)+1)*512);       \
    }                                                                         \
    {                                                                         \
      bf16x8 af = *(const bf16x8*)&A_s[CUR][(w*64 + l)*8];                    \
      _Pragma("unroll")                                                       \
      for (int nf = 0; nf < 16; ++nf)                                         \
        acc[nf] = __builtin_amdgcn_mfma_f32_16x16x32_bf16(af, BCUR[nf],       \
                                                          acc[nf], 0,0,0);    \
    }                                                                         \
    __syncthreads();                                                          \
    if ((KT) < 15) *(bf16x8*)&A_s[(CUR)^1][tid*8] = cvt8(a0r, a1r);           \
  }

  for (int kt2 = 0; kt2 < 16; kt2 += 2){
    SCORE_STEP(0, b0, b1, kt2);
    SCORE_STEP(1, b1, b0, kt2+1);
  }
#undef SCORE_STEP

  // epilogue: s[t] = sum_a tanh(pe + ph[a]) * w2[a]; D: row=g*4+r, col=la
  #pragma unroll
  for (int r = 0; r < 4; ++r){
    float s = 0.f;
    #pragma unroll
    for (int nf = 0; nf < 16; ++nf){
      float v = acc[nf][r] + ph_s[nf*16 + la];
      s += tanh_f(v) * w2_s[nf*16 + la];
    }
    s += __shfl_xor(s, 1, 16);
    s += __shfl_xor(s, 2, 16);
    s += __shfl_xor(s, 4, 16);
    s += __shfl_xor(s, 8, 16);
    if (la == 0){
      int t = tc*64 + w*16 + g*4 + r;
      scores[b*512 + t] = s;
    }
  }
}

// ---------------- softmax over T=512 per batch row (in-place ok) ----------------
__global__ void k_softmax(const float* __restrict__ scores, const unsigned char* __restrict__ mask,
                          float* __restrict__ aw)
{
  const int b = blockIdx.x, tid = threadIdx.x;
  float s0 = scores[b*512 + tid];
  float s1 = scores[b*512 + 256 + tid];
  if (mask[b*512 + tid])       s0 = -1e30f;
  if (mask[b*512 + 256 + tid]) s1 = -1e30f;
  float m = fmaxf(s0, s1);
  #pragma unroll
  for (int o = 32; o; o >>= 1) m = fmaxf(m, __shfl_xor(m, o, 64));
  __shared__ float redm[4], reds[4];
  const int wv = tid >> 6, lx = tid & 63;
  if (lx == 0) redm[wv] = m;
  __syncthreads();
  m = fmaxf(fmaxf(redm[0], redm[1]), fmaxf(redm[2], redm[3]));
  float e0 = __expf(s0 - m), e1 = __expf(s1 - m);
  float ss = e0 + e1;
  #pragma unroll
  for (int o = 32; o; o >>= 1) ss += __shfl_xor(ss, o, 64);
  if (lx == 0) reds[wv] = ss;
  __syncthreads();
  ss = reds[0] + reds[1] + reds[2] + reds[3];
  float inv = 1.f / ss;
  aw[b*512 + tid]       = e0 * inv;
  aw[b*512 + 256 + tid] = e1 * inv;
}

// ---------------- ctxt partials (f32 enc, float4/lane, 2-way t-split, 4-acc ILP) --
__global__ void k_ctxt(const float* __restrict__ enc, const float* __restrict__ aw,
                       float* __restrict__ part)
{
  const int b = blockIdx.x, q = blockIdx.y, tid = threadIdx.x;
  const int tr = tid >> 7, ec = tid & 127;
  __shared__ float aw_s[128];
  if (tid < 128) aw_s[tid] = aw[b*512 + q*128 + tid];
  __syncthreads();
  const float* ep = enc + ((size_t)b*512 + q*128 + tr*64)*512 + ec*4;
  f32x4 sA = {0.f,0.f,0.f,0.f}, sB = sA, sC = sA, sD = sA;
  for (int t = 0; t < 64; t += 4){
    f32x4 e0 = *(const f32x4*)(ep + (size_t)(t  )*512);
    f32x4 e1 = *(const f32x4*)(ep + (size_t)(t+1)*512);
    f32x4 e2 = *(const f32x4*)(ep + (size_t)(t+2)*512);
    f32x4 e3 = *(const f32x4*)(ep + (size_t)(t+3)*512);
    sA += e0 * aw_s[tr*64 + t];
    sB += e1 * aw_s[tr*64 + t+1];
    sC += e2 * aw_s[tr*64 + t+2];
    sD += e3 * aw_s[tr*64 + t+3];
  }
  f32x4 s = (sA + sB) + (sC + sD);
  __shared__ f32x4 red[128];
  if (tr == 1) red[ec] = s;
  __syncthreads();
  if (tr == 0){
    s += red[ec];
    *(f32x4*)(part + ((size_t)q*128 + b)*512 + ec*4) = s;
  }
}

// ---------------- finalize ctxt -> xh[:,512:1024], hc[:,1024:1536] ----------------
__global__ void k_ctxt_fin(const float* __restrict__ part, float* __restrict__ xh,
                           float* __restrict__ hc)
{
  const int b = blockIdx.x, tid = threadIdx.x;
  const int e = tid*2;
  float sx = 0.f, sy = 0.f;
  #pragma unroll
  for (int q = 0; q < 4; ++q){
    float2 p = *(const float2*)(part + ((size_t)q*128 + b)*512 + e);
    sx += p.x; sy += p.y;
  }
  float2 r; r.x = sx; r.y = sy;
  *(float2*)(xh + (size_t)b*2048 + 512 + e) = r;
  *(float2*)(hc + (size_t)b*1536 + 1024 + e) = r;
}

// ---------------- partial GEMM: Cpart[kc][128][N] = A[:,koff:koff+Kloc] @ W^T ------
// W row j: k<ksplit -> W1[j,k], else W2[j,k-ksplit]. kc = blockIdx.y.
__global__ __launch_bounds__(256,2) void k_gemm_part(
    const float* __restrict__ A, int lda,
    const float* __restrict__ W1, int ldw1,
    const float* __restrict__ W2, int ldw2, int ksplit,
    float* __restrict__ Cpart, int ldc, int Kloc)
{
  const int jt = blockIdx.x * 32;
  const int kc = blockIdx.y;
  const int koff = kc * Kloc;
  const int tid = threadIdx.x;
  const int w = tid >> 6, lane = tid & 63;
  const int la = lane & 15, g = lane >> 4;

  __shared__ __align__(16) __bf16 A_s[128][40];
  __shared__ __align__(16) __bf16 B_s[32][40];

  f32x4 acc[2][2];
  #pragma unroll
  for (int i = 0; i < 2; ++i)
    #pragma unroll
    for (int j = 0; j < 2; ++j) acc[i][j] = (f32x4){0.f,0.f,0.f,0.f};

  const int ar = tid >> 1, ac = (tid & 1) * 16;
  const int br = tid >> 3, bc = (tid & 7) * 4;

  for (int kl = 0; kl < Kloc; kl += 32){
    const int kk = koff + kl;
    {
      const float* p = A + (size_t)ar*lda + kk + ac;
      float4 v0 = *(const float4*)(p);
      float4 v1 = *(const float4*)(p+4);
      float4 v2 = *(const float4*)(p+8);
      float4 v3 = *(const float4*)(p+12);
      *(bf16x8*)&A_s[ar][ac]   = cvt8(v0,v1);
      *(bf16x8*)&A_s[ar][ac+8] = cvt8(v2,v3);
    }
    {
      const float* wp = (kk < ksplit)
          ? (W1 + (size_t)(jt+br)*ldw1 + kk + bc)
          : (W2 + (size_t)(jt+br)*ldw2 + (kk - ksplit) + bc);
      float4 v = *(const float4*)wp;
      bf16x4 bv;
      bv[0]=(__bf16)v.x; bv[1]=(__bf16)v.y; bv[2]=(__bf16)v.z; bv[3]=(__bf16)v.w;
      *(bf16x4*)&B_s[br][bc] = bv;
    }
    __syncthreads();
    bf16x8 a0 = *(const bf16x8*)&A_s[w*32 + la][g*8];
    bf16x8 a1 = *(const bf16x8*)&A_s[w*32 + 16 + la][g*8];
    bf16x8 b0 = *(const bf16x8*)&B_s[la][g*8];
    bf16x8 b1 = *(const bf16x8*)&B_s[16 + la][g*8];
    acc[0][0] = __builtin_amdgcn_mfma_f32_16x16x32_bf16(a0, b0, acc[0][0], 0,0,0);
    acc[0][1] = __builtin_amdgcn_mfma_f32_16x16x32_bf16(a0, b1, acc[0][1], 0,0,0);
    acc[1][0] = __builtin_amdgcn_mfma_f32_16x16x32_bf16(a1, b0, acc[1][0], 0,0,0);
    acc[1][1] = __builtin_amdgcn_mfma_f32_16x16x32_bf16(a1, b1, acc[1][1], 0,0,0);
    __syncthreads();
  }

  float* cp = Cpart + (size_t)kc*128*ldc;
  #pragma unroll
  for (int mfi = 0; mfi < 2; ++mfi)
    #pragma unroll
    for (int nf = 0; nf < 2; ++nf)
      #pragma unroll
      for (int r = 0; r < 4; ++r){
        int m = w*32 + mfi*16 + g*4 + r;
        int j = jt + nf*16 + la;
        cp[(size_t)m*ldc + j] = acc[mfi][nf][r];
      }
}

// ---------------- LSTM finisher: sum 4 partials + biases + pointwise ----------------
__global__ void k_lstm_fin(const float* __restrict__ partG, const float* __restrict__ b_ih,
                           const float* __restrict__ b_hh, const float* __restrict__ c0,
                           float* __restrict__ out, float* __restrict__ hc)
{
  const int idx = blockIdx.x*256 + threadIdx.x;   // 0..131071
  const int b = idx >> 10, h = idx & 1023;
  float gi = b_ih[h]        + b_hh[h];
  float gf = b_ih[1024 + h] + b_hh[1024 + h];
  float gg = b_ih[2048 + h] + b_hh[2048 + h];
  float go = b_ih[3072 + h] + b_hh[3072 + h];
  #pragma unroll
  for (int kc = 0; kc < 4; ++kc){
    const float* gp = partG + ((size_t)kc*128 + b)*4096;
    gi += gp[h]; gf += gp[1024 + h]; gg += gp[2048 + h]; go += gp[3072 + h];
  }
  float c1 = sigf(gf)*c0[idx] + sigf(gi)*tanh_f(gg);
  float h1 = sigf(go)*tanh_f(c1);
  out[131072 + idx] = h1;
  out[262144 + idx] = c1;
  hc[(size_t)b*1536 + h] = h1;
}

// ---------------- proj finisher: sum 4 partials + bias + tanh -> out[:131072] ------
__global__ void k_proj_fin(const float* __restrict__ partP, const float* __restrict__ b_proj,
                           float* __restrict__ out)
{
  const int idx = blockIdx.x*256 + threadIdx.x;   // 0..131071
  const int b = idx >> 10, j = idx & 1023;
  float s = b_proj[j];
  #pragma unroll
  for (int kc = 0; kc < 4; ++kc)
    s += partP[((size_t)kc*128 + b)*1024 + j];
  out[idx] = tanh_f(s);
}

extern "C" void kernel_launch(void* const* d_in, const int* in_sizes, int n_in,
                              void* d_out, int out_size, void* d_ws, size_t ws_size,
                              hipStream_t stream)
{
  const float* embed  = (const float*)d_in[0];
  const float* h0     = (const float*)d_in[1];
  const float* c0     = (const float*)d_in[2];
  const float* enc    = (const float*)d_in[3];
  const float* W_ph   = (const float*)d_in[4];
  const float* W_pe   = (const float*)d_in[5];
  const float* w_fc2  = (const float*)d_in[6];
  const float* W_ih   = (const float*)d_in[7];
  const float* W_hh   = (const float*)d_in[8];
  const float* b_ih   = (const float*)d_in[9];
  const float* b_hh   = (const float*)d_in[10];
  const float* W_proj = (const float*)d_in[11];
  const float* b_proj = (const float*)d_in[12];
  const unsigned char* mask = (const unsigned char*)d_in[13];

  float* ws     = (float*)d_ws;
  float* ph     = ws;                   //   32768
  float* scores = ws + 32768;           //   65536 (aw in place)
  float* part   = ws + 98304;           //  262144 (4 x 128 x 512)
  float* xh     = ws + 360448;          //  262144 (128x2048: [embed|ctxt|h])
  float* hc     = ws + 622592;          //  196608 (128x1536: [h1|ctxt])
  float* partG  = ws + 819200;          // 2097152 (4 x 128 x 4096)
  float* partP  = ws + 2916352;         //  524288 (4 x 128 x 1024)
  __bf16* wpeX  = (__bf16*)(ws + 3440640);   // 131072 bf16
  float* out    = (float*)d_out;

  k_frag   <<<64, 256, 0, stream>>>(W_pe, wpeX);
  k_ph     <<<128, 256, 0, stream>>>(h0, W_ph, ph);
  k_concat <<<128, 256, 0, stream>>>(embed, h0, xh);
  k_scores <<<dim3(8,128), 256, 0, stream>>>(enc, wpeX, ph, w_fc2, scores);
  k_softmax<<<128, 256, 0, stream>>>(scores, mask, scores);
  k_ctxt   <<<dim3(128,4), 256, 0, stream>>>(enc, scores, part);
  k_ctxt_fin<<<128, 256, 0, stream>>>(part, xh, hc);
  k_gemm_part<<<dim3(128,4), 256, 0, stream>>>(xh, 2048, W_ih, 1024, W_hh, 1024, 1024,
                                               partG, 4096, 512);
  k_lstm_fin<<<512, 256, 0, stream>>>(partG, b_ih, b_hh, c0, out, hc);
  k_gemm_part<<<dim3(32,4), 256, 0, stream>>>(hc, 1536, W_proj, 1536, nullptr, 0, 1536,
                                              partP, 1024, 384);
  k_proj_fin<<<512, 256, 0, stream>>>(partP, b_proj, out);
}

// Round 5
// 141.238 us; speedup vs baseline: 1.8238x; 1.1146x over previous
//
#include <hip/hip_runtime.h>
#include <cstddef>

typedef float  f32x4  __attribute__((ext_vector_type(4)));
typedef __bf16 bf16x8 __attribute__((ext_vector_type(8)));
typedef __bf16 bf16x4 __attribute__((ext_vector_type(4)));

#define DEV static __device__ __forceinline__

DEV float sigf(float x){ return 1.f/(1.f+__expf(-x)); }
DEV float tanh_f(float x){
  x = fminf(fmaxf(x, -20.f), 20.f);
  float e = __expf(2.f*x);
  return (e-1.f)/(e+1.f);
}

DEV bf16x8 cvt8(const float4 a, const float4 b){
  bf16x8 r;
  r[0]=(__bf16)a.x; r[1]=(__bf16)a.y; r[2]=(__bf16)a.z; r[3]=(__bf16)a.w;
  r[4]=(__bf16)b.x; r[5]=(__bf16)b.y; r[6]=(__bf16)b.z; r[7]=(__bf16)b.w;
  return r;
}

// ---------------- fragment-layout convert (W_pe only): f32 -> bf16 MFMA tiles ----
// lane l of tile (gt,sub) holds src[gt*16 + (l&15)][sub*32 + (l>>4)*8 .. +8]
__global__ void k_frag(const float* __restrict__ src, __bf16* __restrict__ dst)
{
  const int idx = blockIdx.x*256 + threadIdx.x;
  const int l   = idx & 63;
  const int sub = (idx >> 6) & 15;
  const int gt  = idx >> 10;
  const float* p = src + ((size_t)gt*16 + (l&15))*512 + sub*32 + (l>>4)*8;
  float4 v0 = *(const float4*)p;
  float4 v1 = *(const float4*)(p+4);
  *(bf16x8*)(dst + ((size_t)(gt*16 + sub)*64 + l)*8) = cvt8(v0, v1);
}

// ---------------- ph = h_last @ W_ph^T : (128,256) ----------------
__global__ void k_ph(const float* __restrict__ h0, const float* __restrict__ W_ph,
                     float* __restrict__ ph)
{
  const int b = blockIdx.x, a = threadIdx.x;
  __shared__ float h_s[1024];
  for (int k = a; k < 1024; k += 256) h_s[k] = h0[(size_t)b*1024 + k];
  __syncthreads();
  const float* wr = W_ph + (size_t)a*1024;
  float acc = 0.f;
  for (int k = 0; k < 1024; k += 4){
    float4 w = *(const float4*)(wr + k);
    acc += w.x*h_s[k] + w.y*h_s[k+1] + w.z*h_s[k+2] + w.w*h_s[k+3];
  }
  ph[b*256 + a] = acc;
}

// ---------------- xh[:,0:512]=embed, xh[:,1024:2048]=h0 ----------------
__global__ void k_concat(const float* __restrict__ embed, const float* __restrict__ h0,
                         float* __restrict__ xh)
{
  const int b = blockIdx.x, tid = threadIdx.x;
  *(float2*)(xh + (size_t)b*2048 + tid*2) = *(const float2*)(embed + (size_t)b*512 + tid*2);
  *(float4*)(xh + (size_t)b*2048 + 1024 + tid*4) = *(const float4*)(h0 + (size_t)b*1024 + tid*4);
}

// ---------------- scores: B fully LDS-resident (per K-half), A global->reg ------
// block: 256 t x 256 a, 512 threads (8 waves x 32 t). K=512 in 2 halves of 8 kt.
__global__ __launch_bounds__(512,2) void k_scores(
    const float* __restrict__ enc, const __bf16* __restrict__ wpeX,
    const float* __restrict__ ph, const float* __restrict__ w_fc2,
    float* __restrict__ scores)
{
  const int b  = blockIdx.y;
  const int tc = blockIdx.x;            // t-chunk of 256
  const int tid = threadIdx.x;
  const int w = tid >> 6, l = tid & 63;
  const int la = l & 15, g = l >> 4;

  __shared__ __align__(16) __bf16 B_s[128*512];  // 128 KB: frag c=nf*8+ktl at c*512
  __shared__ float ph_s[256], w2_s[256];
  if (tid < 256){ ph_s[tid] = ph[b*256 + tid]; w2_s[tid] = w_fc2[tid]; }

  // wave's A rows: lane l covers row (tc*256 + w*32 + mfi*16 + la), k-cols g*8..+8
  const float* ag = enc + ((size_t)b*512 + tc*256 + w*32 + la)*512 + g*8;

  f32x4 acc[2][16];
  #pragma unroll
  for (int i = 0; i < 2; ++i)
    #pragma unroll
    for (int j = 0; j < 16; ++j) acc[i][j] = (f32x4){0.f,0.f,0.f,0.f};

  float4 ac00 = *(const float4*)(ag);
  float4 ac01 = *(const float4*)(ag + 4);
  float4 ac10 = *(const float4*)(ag + 16*512);
  float4 ac11 = *(const float4*)(ag + 16*512 + 4);
  float4 an00, an01, an10, an11;

  #pragma unroll
  for (int h = 0; h < 2; ++h){
    if (h) __syncthreads();             // all reads of previous half done
    // stage B half h: 128 KB, 256 B/thread, coalesced 1KB per 64 lanes
    #pragma unroll
    for (int i = 0; i < 16; ++i){
      const int s = i*512 + tid;
      const int c = s >> 6, ll = s & 63;
      const int nf = c >> 3, kl2 = c & 7;
      bf16x8 v = *(const bf16x8*)(wpeX + ((size_t)(nf*16 + h*8 + kl2)*64 + ll)*8);
      *(bf16x8*)(B_s + (size_t)s*8) = v;
    }
    __syncthreads();

    #pragma unroll
    for (int ktl = 0; ktl < 8; ++ktl){
      const int kt = h*8 + ktl;
      if (kt < 15){                     // prefetch next kt's A into regs
        const int ko = (kt+1)*32;
        an00 = *(const float4*)(ag + ko);
        an01 = *(const float4*)(ag + ko + 4);
        an10 = *(const float4*)(ag + 16*512 + ko);
        an11 = *(const float4*)(ag + 16*512 + ko + 4);
      }
      bf16x8 af0 = cvt8(ac00, ac01);
      bf16x8 af1 = cvt8(ac10, ac11);
      #pragma unroll
      for (int nfg = 0; nfg < 2; ++nfg){
        bf16x8 bf[8];
        #pragma unroll
        for (int j = 0; j < 8; ++j)
          bf[j] = *(const bf16x8*)(B_s + (size_t)(((nfg*8+j)*8 + ktl)*64 + l)*8);
        #pragma unroll
        for (int j = 0; j < 8; ++j){
          const int nf = nfg*8 + j;
          acc[0][nf] = __builtin_amdgcn_mfma_f32_16x16x32_bf16(af0, bf[j], acc[0][nf], 0,0,0);
          acc[1][nf] = __builtin_amdgcn_mfma_f32_16x16x32_bf16(af1, bf[j], acc[1][nf], 0,0,0);
        }
      }
      if (kt < 15){ ac00 = an00; ac01 = an01; ac10 = an10; ac11 = an11; }
    }
  }

  // epilogue: s[t] = sum_a tanh(pe + ph[a]) * w2[a]; D: row=g*4+r, col=la
  #pragma unroll
  for (int mfi = 0; mfi < 2; ++mfi){
    #pragma unroll
    for (int r = 0; r < 4; ++r){
      float s = 0.f;
      #pragma unroll
      for (int nf = 0; nf < 16; ++nf){
        float v = acc[mfi][nf][r] + ph_s[nf*16 + la];
        s += tanh_f(v) * w2_s[nf*16 + la];
      }
      s += __shfl_xor(s, 1, 16);
      s += __shfl_xor(s, 2, 16);
      s += __shfl_xor(s, 4, 16);
      s += __shfl_xor(s, 8, 16);
      if (la == 0){
        int t = tc*256 + w*32 + mfi*16 + g*4 + r;
        scores[b*512 + t] = s;
      }
    }
  }
}

// ---------------- softmax over T=512 per batch row (in-place ok) ----------------
__global__ void k_softmax(const float* __restrict__ scores, const unsigned char* __restrict__ mask,
                          float* __restrict__ aw)
{
  const int b = blockIdx.x, tid = threadIdx.x;
  float s0 = scores[b*512 + tid];
  float s1 = scores[b*512 + 256 + tid];
  if (mask[b*512 + tid])       s0 = -1e30f;
  if (mask[b*512 + 256 + tid]) s1 = -1e30f;
  float m = fmaxf(s0, s1);
  #pragma unroll
  for (int o = 32; o; o >>= 1) m = fmaxf(m, __shfl_xor(m, o, 64));
  __shared__ float redm[4], reds[4];
  const int wv = tid >> 6, lx = tid & 63;
  if (lx == 0) redm[wv] = m;
  __syncthreads();
  m = fmaxf(fmaxf(redm[0], redm[1]), fmaxf(redm[2], redm[3]));
  float e0 = __expf(s0 - m), e1 = __expf(s1 - m);
  float ss = e0 + e1;
  #pragma unroll
  for (int o = 32; o; o >>= 1) ss += __shfl_xor(ss, o, 64);
  if (lx == 0) reds[wv] = ss;
  __syncthreads();
  ss = reds[0] + reds[1] + reds[2] + reds[3];
  float inv = 1.f / ss;
  aw[b*512 + tid]       = e0 * inv;
  aw[b*512 + 256 + tid] = e1 * inv;
}

// ---------------- ctxt partials (f32 enc, float4/lane, 2-way t-split, 4-acc ILP) --
__global__ void k_ctxt(const float* __restrict__ enc, const float* __restrict__ aw,
                       float* __restrict__ part)
{
  const int b = blockIdx.x, q = blockIdx.y, tid = threadIdx.x;
  const int tr = tid >> 7, ec = tid & 127;
  __shared__ float aw_s[128];
  if (tid < 128) aw_s[tid] = aw[b*512 + q*128 + tid];
  __syncthreads();
  const float* ep = enc + ((size_t)b*512 + q*128 + tr*64)*512 + ec*4;
  f32x4 sA = {0.f,0.f,0.f,0.f}, sB = sA, sC = sA, sD = sA;
  for (int t = 0; t < 64; t += 4){
    f32x4 e0 = *(const f32x4*)(ep + (size_t)(t  )*512);
    f32x4 e1 = *(const f32x4*)(ep + (size_t)(t+1)*512);
    f32x4 e2 = *(const f32x4*)(ep + (size_t)(t+2)*512);
    f32x4 e3 = *(const f32x4*)(ep + (size_t)(t+3)*512);
    sA += e0 * aw_s[tr*64 + t];
    sB += e1 * aw_s[tr*64 + t+1];
    sC += e2 * aw_s[tr*64 + t+2];
    sD += e3 * aw_s[tr*64 + t+3];
  }
  f32x4 s = (sA + sB) + (sC + sD);
  __shared__ f32x4 red[128];
  if (tr == 1) red[ec] = s;
  __syncthreads();
  if (tr == 0){
    s += red[ec];
    *(f32x4*)(part + ((size_t)q*128 + b)*512 + ec*4) = s;
  }
}

// ---------------- finalize ctxt -> xh[:,512:1024], hc[:,1024:1536] ----------------
__global__ void k_ctxt_fin(const float* __restrict__ part, float* __restrict__ xh,
                           float* __restrict__ hc)
{
  const int b = blockIdx.x, tid = threadIdx.x;
  const int e = tid*2;
  float sx = 0.f, sy = 0.f;
  #pragma unroll
  for (int q = 0; q < 4; ++q){
    float2 p = *(const float2*)(part + ((size_t)q*128 + b)*512 + e);
    sx += p.x; sy += p.y;
  }
  float2 r; r.x = sx; r.y = sy;
  *(float2*)(xh + (size_t)b*2048 + 512 + e) = r;
  *(float2*)(hc + (size_t)b*1536 + 1024 + e) = r;
}

// ---------------- partial GEMM: Cpart[kc][128][N] = A[:,koff:koff+Kloc] @ W^T ------
__global__ __launch_bounds__(256,2) void k_gemm_part(
    const float* __restrict__ A, int lda,
    const float* __restrict__ W1, int ldw1,
    const float* __restrict__ W2, int ldw2, int ksplit,
    float* __restrict__ Cpart, int ldc, int Kloc)
{
  const int jt = blockIdx.x * 32;
  const int kc = blockIdx.y;
  const int koff = kc * Kloc;
  const int tid = threadIdx.x;
  const int w = tid >> 6, lane = tid & 63;
  const int la = lane & 15, g = lane >> 4;

  __shared__ __align__(16) __bf16 A_s[128][40];
  __shared__ __align__(16) __bf16 B_s[32][40];

  f32x4 acc[2][2];
  #pragma unroll
  for (int i = 0; i < 2; ++i)
    #pragma unroll
    for (int j = 0; j < 2; ++j) acc[i][j] = (f32x4){0.f,0.f,0.f,0.f};

  const int ar = tid >> 1, ac = (tid & 1) * 16;
  const int br = tid >> 3, bc = (tid & 7) * 4;

  for (int kl = 0; kl < Kloc; kl += 32){
    const int kk = koff + kl;
    {
      const float* p = A + (size_t)ar*lda + kk + ac;
      float4 v0 = *(const float4*)(p);
      float4 v1 = *(const float4*)(p+4);
      float4 v2 = *(const float4*)(p+8);
      float4 v3 = *(const float4*)(p+12);
      *(bf16x8*)&A_s[ar][ac]   = cvt8(v0,v1);
      *(bf16x8*)&A_s[ar][ac+8] = cvt8(v2,v3);
    }
    {
      const float* wp = (kk < ksplit)
          ? (W1 + (size_t)(jt+br)*ldw1 + kk + bc)
          : (W2 + (size_t)(jt+br)*ldw2 + (kk - ksplit) + bc);
      float4 v = *(const float4*)wp;
      bf16x4 bv;
      bv[0]=(__bf16)v.x; bv[1]=(__bf16)v.y; bv[2]=(__bf16)v.z; bv[3]=(__bf16)v.w;
      *(bf16x4*)&B_s[br][bc] = bv;
    }
    __syncthreads();
    bf16x8 a0 = *(const bf16x8*)&A_s[w*32 + la][g*8];
    bf16x8 a1 = *(const bf16x8*)&A_s[w*32 + 16 + la][g*8];
    bf16x8 b0 = *(const bf16x8*)&B_s[la][g*8];
    bf16x8 b1 = *(const bf16x8*)&B_s[16 + la][g*8];
    acc[0][0] = __builtin_amdgcn_mfma_f32_16x16x32_bf16(a0, b0, acc[0][0], 0,0,0);
    acc[0][1] = __builtin_amdgcn_mfma_f32_16x16x32_bf16(a0, b1, acc[0][1], 0,0,0);
    acc[1][0] = __builtin_amdgcn_mfma_f32_16x16x32_bf16(a1, b0, acc[1][0], 0,0,0);
    acc[1][1] = __builtin_amdgcn_mfma_f32_16x16x32_bf16(a1, b1, acc[1][1], 0,0,0);
    __syncthreads();
  }

  float* cp = Cpart + (size_t)kc*128*ldc;
  #pragma unroll
  for (int mfi = 0; mfi < 2; ++mfi)
    #pragma unroll
    for (int nf = 0; nf < 2; ++nf)
      #pragma unroll
      for (int r = 0; r < 4; ++r){
        int m = w*32 + mfi*16 + g*4 + r;
        int j = jt + nf*16 + la;
        cp[(size_t)m*ldc + j] = acc[mfi][nf][r];
      }
}

// ---------------- LSTM finisher: sum 4 partials + biases + pointwise ----------------
__global__ void k_lstm_fin(const float* __restrict__ partG, const float* __restrict__ b_ih,
                           const float* __restrict__ b_hh, const float* __restrict__ c0,
                           float* __restrict__ out, float* __restrict__ hc)
{
  const int idx = blockIdx.x*256 + threadIdx.x;   // 0..131071
  const int b = idx >> 10, h = idx & 1023;
  float gi = b_ih[h]        + b_hh[h];
  float gf = b_ih[1024 + h] + b_hh[1024 + h];
  float gg = b_ih[2048 + h] + b_hh[2048 + h];
  float go = b_ih[3072 + h] + b_hh[3072 + h];
  #pragma unroll
  for (int kc = 0; kc < 4; ++kc){
    const float* gp = partG + ((size_t)kc*128 + b)*4096;
    gi += gp[h]; gf += gp[1024 + h]; gg += gp[2048 + h]; go += gp[3072 + h];
  }
  float c1 = sigf(gf)*c0[idx] + sigf(gi)*tanh_f(gg);
  float h1 = sigf(go)*tanh_f(c1);
  out[131072 + idx] = h1;
  out[262144 + idx] = c1;
  hc[(size_t)b*1536 + h] = h1;
}

// ---------------- proj finisher: sum 4 partials + bias + tanh -> out[:131072] ------
__global__ void k_proj_fin(const float* __restrict__ partP, const float* __restrict__ b_proj,
                           float* __restrict__ out)
{
  const int idx = blockIdx.x*256 + threadIdx.x;   // 0..131071
  const int b = idx >> 10, j = idx & 1023;
  float s = b_proj[j];
  #pragma unroll
  for (int kc = 0; kc < 4; ++kc)
    s += partP[((size_t)kc*128 + b)*1024 + j];
  out[idx] = tanh_f(s);
}

extern "C" void kernel_launch(void* const* d_in, const int* in_sizes, int n_in,
                              void* d_out, int out_size, void* d_ws, size_t ws_size,
                              hipStream_t stream)
{
  const float* embed  = (const float*)d_in[0];
  const float* h0     = (const float*)d_in[1];
  const float* c0     = (const float*)d_in[2];
  const float* enc    = (const float*)d_in[3];
  const float* W_ph   = (const float*)d_in[4];
  const float* W_pe   = (const float*)d_in[5];
  const float* w_fc2  = (const float*)d_in[6];
  const float* W_ih   = (const float*)d_in[7];
  const float* W_hh   = (const float*)d_in[8];
  const float* b_ih   = (const float*)d_in[9];
  const float* b_hh   = (const float*)d_in[10];
  const float* W_proj = (const float*)d_in[11];
  const float* b_proj = (const float*)d_in[12];
  const unsigned char* mask = (const unsigned char*)d_in[13];

  float* ws     = (float*)d_ws;
  float* ph     = ws;                   //   32768
  float* scores = ws + 32768;           //   65536 (aw in place)
  float* part   = ws + 98304;           //  262144 (4 x 128 x 512)
  float* xh     = ws + 360448;          //  262144 (128x2048: [embed|ctxt|h])
  float* hc     = ws + 622592;          //  196608 (128x1536: [h1|ctxt])
  float* partG  = ws + 819200;          // 2097152 (4 x 128 x 4096)
  float* partP  = ws + 2916352;         //  524288 (4 x 128 x 1024)
  __bf16* wpeX  = (__bf16*)(ws + 3440640);   // 131072 bf16
  float* out    = (float*)d_out;

  k_frag   <<<64, 256, 0, stream>>>(W_pe, wpeX);
  k_ph     <<<128, 256, 0, stream>>>(h0, W_ph, ph);
  k_concat <<<128, 256, 0, stream>>>(embed, h0, xh);
  k_scores <<<dim3(2,128), 512, 0, stream>>>(enc, wpeX, ph, w_fc2, scores);
  k_softmax<<<128, 256, 0, stream>>>(scores, mask, scores);
  k_ctxt   <<<dim3(128,4), 256, 0, stream>>>(enc, scores, part);
  k_ctxt_fin<<<128, 256, 0, stream>>>(part, xh, hc);
  k_gemm_part<<<dim3(128,4), 256, 0, stream>>>(xh, 2048, W_ih, 1024, W_hh, 1024, 1024,
                                               partG, 4096, 512);
  k_lstm_fin<<<512, 256, 0, stream>>>(partG, b_ih, b_hh, c0, out, hc);
  k_gemm_part<<<dim3(32,4), 256, 0, stream>>>(hc, 1536, W_proj, 1536, nullptr, 0, 1536,
                                              partP, 1024, 384);
  k_proj_fin<<<512, 256, 0, stream>>>(partP, b_proj, out);
}